// Round 1
// baseline (584.063 us; speedup 1.0000x reference)
//
#include <hip/hip_runtime.h>
#include <hip/hip_bf16.h>

typedef unsigned short u16;
typedef __attribute__((ext_vector_type(4))) float f32x4;
typedef __attribute__((ext_vector_type(8))) __bf16 bf16x8;
typedef __attribute__((ext_vector_type(8))) unsigned short ushort8;

#define Bb 16
#define Ss 512
#define Hh 1024
#define Ee 256
#define Vv 50257
#define Mm 8192  // Ss*Bb

// ---- workspace layout (bytes) ----
#define WS_ENC_BF   0           // 8192*1024 u16 = 16777216
#define WS_W2_BF    16777216    // 1024*1024 u16 = 2097152
#define WS_DPW      18874368    // 16*1024 f32 (dec_proj + w1_b + w2_b)
#define WS_SCORE    18939904    // 8192 f32
#define WS_GRUIN    18972672    // 16*1280 f32
#define WS_GI       19054592    // 16*3072 f32
// total 19251200 B

__device__ __forceinline__ u16 f2bf(float f) {
  unsigned u = __float_as_uint(f);
  return (u16)((u + 0x7FFFu + ((u >> 16) & 1u)) >> 16);  // RNE
}

__device__ __forceinline__ void gl2lds16(const void* g, void* l) {
  __builtin_amdgcn_global_load_lds((__attribute__((address_space(1))) void*)g,
                                   (__attribute__((address_space(3))) void*)l,
                                   16, 0, 0);
}

// ---------- kernel 0: fp32 -> bf16 convert (enc_output then w2_W) ----------
__global__ __launch_bounds__(256) void k_cvt2(const float* __restrict__ enc, u16* __restrict__ encb,
                                              const float* __restrict__ w2, u16* __restrict__ w2b) {
  int i = blockIdx.x * 256 + threadIdx.x;  // chunk of 8 floats
  const float* src; u16* dst; int j;
  if (i < 1048576) { src = enc; dst = encb; j = i; }
  else             { src = w2;  dst = w2b;  j = i - 1048576; }
  const float4* s4 = (const float4*)src;
  float4 a = s4[j * 2], c = s4[j * 2 + 1];
  ushort8 o;
  o[0] = f2bf(a.x); o[1] = f2bf(a.y); o[2] = f2bf(a.z); o[3] = f2bf(a.w);
  o[4] = f2bf(c.x); o[5] = f2bf(c.y); o[6] = f2bf(c.z); o[7] = f2bf(c.w);
  *(ushort8*)(dst + j * 8) = o;
}

// ---------- kernel 1: dec_proj (+w1_b+w2_b), score init, gru_in init, emb gather ----------
__global__ __launch_bounds__(256) void k_prep(const float* __restrict__ dec_hs, const float* __restrict__ w1_W,
                                              const float* __restrict__ w1_b, const float* __restrict__ w2_b,
                                              const float* __restrict__ va_b, const int* __restrict__ x,
                                              const float* __restrict__ emb, float* __restrict__ dpw,
                                              float* __restrict__ score, float* __restrict__ gru_in) {
  const int n = blockIdx.x, t = threadIdx.x;
  float acc[16];
#pragma unroll
  for (int b = 0; b < 16; ++b) acc[b] = 0.f;
#pragma unroll
  for (int i = 0; i < 4; ++i) {
    int k = t + i * 256;
    float w = w1_W[n * Hh + k];
#pragma unroll
    for (int b = 0; b < 16; ++b) acc[b] = fmaf(w, dec_hs[b * Hh + k], acc[b]);
  }
#pragma unroll
  for (int m = 1; m < 64; m <<= 1)
#pragma unroll
    for (int b = 0; b < 16; ++b) acc[b] += __shfl_xor(acc[b], m, 64);
  __shared__ float red[4][16];
  int wave = t >> 6, lane = t & 63;
  if (lane == 0)
#pragma unroll
    for (int b = 0; b < 16; ++b) red[wave][b] = acc[b];
  __syncthreads();
  if (t < 16)
    dpw[t * Hh + n] = red[0][t] + red[1][t] + red[2][t] + red[3][t] + w1_b[n] + w2_b[n];
  // side work
  int fid = n * 256 + t;
  if (fid < 16384) { int b = fid >> 10, k = fid & 1023; gru_in[b * 1280 + k] = 0.f; }
  int sid = fid - 16384;
  if (sid >= 0 && sid < Mm) score[sid] = va_b[0];
  int eid = fid - 24576;
  if (eid >= 0 && eid < 4096) { int b = eid >> 8, j = eid & 255; gru_in[b * 1280 + 1024 + j] = emb[x[b] * Ee + j]; }
}

// ---------- kernel 2: bf16 MFMA GEMM (enc @ w2^T) + fused tanh*va row-reduce -> score ----------
__global__ __launch_bounds__(256) void k_gemm_score(const u16* __restrict__ A, const u16* __restrict__ Bm,
                                                    const float* __restrict__ dpw, const float* __restrict__ vaW,
                                                    float* __restrict__ score) {
  __shared__ __align__(16) u16 Al[4096];  // 128 rows x 32 k
  __shared__ __align__(16) u16 Bl[4096];
  const int tid = threadIdx.x;
  const int wave = tid >> 6, lane = tid & 63;
  const int quad = lane >> 4, l16 = lane & 15;
  const int m0 = blockIdx.x * 128, n0 = blockIdx.y * 128;
  const int wm = (wave & 1) * 64, wn = (wave >> 1) * 64;

  f32x4 acc[4][4];
#pragma unroll
  for (int i = 0; i < 4; ++i)
#pragma unroll
    for (int j = 0; j < 4; ++j) acc[i][j] = (f32x4){0.f, 0.f, 0.f, 0.f};

  const u16* gA = A + (m0 + (tid >> 2)) * 1024 + (tid & 3) * 8;
  const u16* gB = Bm + (n0 + (tid >> 2)) * 1024 + (tid & 3) * 8;
  u16* lA0 = &Al[(wave * 64) * 8];
  u16* lA1 = &Al[(256 + wave * 64) * 8];
  u16* lB0 = &Bl[(wave * 64) * 8];
  u16* lB1 = &Bl[(256 + wave * 64) * 8];

  for (int kt = 0; kt < 1024; kt += 32) {
    __syncthreads();
    gl2lds16(gA + kt, lA0);
    gl2lds16(gA + 64 * 1024 + kt, lA1);
    gl2lds16(gB + kt, lB0);
    gl2lds16(gB + 64 * 1024 + kt, lB1);
    __syncthreads();
    bf16x8 af[4], bfr[4];
#pragma unroll
    for (int i = 0; i < 4; ++i) {
      af[i]  = *(const bf16x8*)&Al[(wm + i * 16 + l16) * 32 + quad * 8];
      bfr[i] = *(const bf16x8*)&Bl[(wn + i * 16 + l16) * 32 + quad * 8];
    }
#pragma unroll
    for (int i = 0; i < 4; ++i)
#pragma unroll
      for (int j = 0; j < 4; ++j)
        acc[i][j] = __builtin_amdgcn_mfma_f32_16x16x32_bf16(af[i], bfr[j], acc[i][j], 0, 0, 0);
  }

  // epilogue: t = tanh(acc + dpw[b][n]) * va[n]; reduce over n; atomic to score[m]
  __syncthreads();
  float* dpw_t = (float*)Al;  // [16][128] = 8KB
  float* va_t  = (float*)Bl;  // [128]
  for (int idx = tid; idx < 2048; idx += 256) {
    int b = idx >> 7, nn = idx & 127;
    dpw_t[idx] = dpw[b * Hh + n0 + nn];
  }
  if (tid < 128) va_t[tid] = vaW[n0 + tid];
  __syncthreads();

  float rs[4][4];
#pragma unroll
  for (int i = 0; i < 4; ++i)
#pragma unroll
    for (int r = 0; r < 4; ++r) rs[i][r] = 0.f;
#pragma unroll
  for (int i = 0; i < 4; ++i)
#pragma unroll
    for (int j = 0; j < 4; ++j) {
      int nn = wn + j * 16 + l16;
      float va = va_t[nn];
#pragma unroll
      for (int r = 0; r < 4; ++r) {
        float xv = acc[i][j][r] + dpw_t[(quad * 4 + r) * 128 + nn];  // b = quad*4+r
        rs[i][r] += tanhf(xv) * va;
      }
    }
#pragma unroll
  for (int i = 0; i < 4; ++i)
#pragma unroll
    for (int r = 0; r < 4; ++r) {
      float v = rs[i][r];
      v += __shfl_xor(v, 1, 64);
      v += __shfl_xor(v, 2, 64);
      v += __shfl_xor(v, 4, 64);
      v += __shfl_xor(v, 8, 64);
      if (l16 == 0) atomicAdd(&score[m0 + wm + i * 16 + quad * 4 + r], v);
    }
}

// ---------- kernel 3: softmax over S per batch -> attn output ----------
__global__ __launch_bounds__(256) void k_softmax(const float* __restrict__ score, float* __restrict__ attn) {
  const int b = blockIdx.x, t = threadIdx.x;
  __shared__ float red[256];
  float v0 = score[t * Bb + b];
  float v1 = score[(t + 256) * Bb + b];
  red[t] = fmaxf(v0, v1);
  __syncthreads();
  for (int s = 128; s > 0; s >>= 1) { if (t < s) red[t] = fmaxf(red[t], red[t + s]); __syncthreads(); }
  float mx = red[0];
  __syncthreads();
  float e0 = expf(v0 - mx), e1 = expf(v1 - mx);
  red[t] = e0 + e1;
  __syncthreads();
  for (int s = 128; s > 0; s >>= 1) { if (t < s) red[t] += red[t + s]; __syncthreads(); }
  float inv = 1.f / red[0];
  attn[b * Ss + t] = e0 * inv;
  attn[b * Ss + t + 256] = e1 * inv;
}

// ---------- kernel 4: context accumulate into gru_in[:, :1024] ----------
__global__ __launch_bounds__(256) void k_context(const float* __restrict__ attn, const float* __restrict__ enc,
                                                 float* __restrict__ gru_in) {
  const int b = blockIdx.x, sc = blockIdx.y, t = threadIdx.x;
  const int s0 = sc * 16;
  float acc[4] = {0.f, 0.f, 0.f, 0.f};
  for (int s = s0; s < s0 + 16; ++s) {
    float a = attn[b * Ss + s];
    const float* e = enc + (s * Bb + b) * Hh;
#pragma unroll
    for (int hh = 0; hh < 4; ++hh) acc[hh] = fmaf(a, e[t + hh * 256], acc[hh]);
  }
#pragma unroll
  for (int hh = 0; hh < 4; ++hh) atomicAdd(&gru_in[b * 1280 + t + hh * 256], acc[hh]);
}

// ---------- kernel 5: gi = gru_in @ W_ih^T + b_ih ----------
__global__ __launch_bounds__(256) void k_gi(const float* __restrict__ W_ih, const float* __restrict__ gru_in,
                                            const float* __restrict__ b_ih, float* __restrict__ gi) {
  const int n = blockIdx.x, t = threadIdx.x;
  float acc[16];
#pragma unroll
  for (int b = 0; b < 16; ++b) acc[b] = 0.f;
#pragma unroll
  for (int i = 0; i < 5; ++i) {
    int k = t + i * 256;
    float w = W_ih[n * 1280 + k];
#pragma unroll
    for (int b = 0; b < 16; ++b) acc[b] = fmaf(w, gru_in[b * 1280 + k], acc[b]);
  }
#pragma unroll
  for (int m = 1; m < 64; m <<= 1)
#pragma unroll
    for (int b = 0; b < 16; ++b) acc[b] += __shfl_xor(acc[b], m, 64);
  __shared__ float red[4][16];
  int wave = t >> 6, lane = t & 63;
  if (lane == 0)
#pragma unroll
    for (int b = 0; b < 16; ++b) red[wave][b] = acc[b];
  __syncthreads();
  if (t < 16)
    gi[t * 3072 + n] = red[0][t] + red[1][t] + red[2][t] + red[3][t] + b_ih[n];
}

// ---------- kernel 6: GRU gates (h0 = 0 => gh = b_hh; h = (1-z)*n) ----------
__global__ __launch_bounds__(256) void k_gates(const float* __restrict__ gi, const float* __restrict__ b_hh,
                                               float* __restrict__ h_out) {
  int idx = blockIdx.x * 256 + threadIdx.x;  // 16384
  int b = idx >> 10, j = idx & 1023;
  float ir = gi[b * 3072 + j], iz = gi[b * 3072 + 1024 + j], in_ = gi[b * 3072 + 2048 + j];
  float r = 1.f / (1.f + expf(-(ir + b_hh[j])));
  float z = 1.f / (1.f + expf(-(iz + b_hh[1024 + j])));
  float n = tanhf(in_ + r * b_hh[2048 + j]);
  h_out[idx] = (1.f - z) * n;
}

// ---------- kernel 7: fc_out = h @ out_W^T + out_b (h in registers) ----------
__global__ __launch_bounds__(256) void k_fc(const float* __restrict__ out_W, const float* __restrict__ out_b,
                                            const float* __restrict__ h, float* __restrict__ fc) {
  const int tid = threadIdx.x, wave = tid >> 6, lane = tid & 63;
  const int v0 = blockIdx.x * 128;
  float4 hv[4][4];
#pragma unroll
  for (int bb = 0; bb < 4; ++bb)
#pragma unroll
    for (int i = 0; i < 4; ++i)
      hv[bb][i] = *(const float4*)&h[(wave * 4 + bb) * Hh + lane * 16 + i * 4];

  for (int rr = 0; rr < 128; ++rr) {
    int v = v0 + rr;
    if (v >= Vv) break;
    const float4* wr = (const float4*)&out_W[(long)v * Hh + lane * 16];
    float a0 = 0.f, a1 = 0.f, a2 = 0.f, a3 = 0.f;
#pragma unroll
    for (int i = 0; i < 4; ++i) {
      float4 w = wr[i];
      float4 h0 = hv[0][i], h1 = hv[1][i], h2 = hv[2][i], h3 = hv[3][i];
      a0 = fmaf(w.x, h0.x, a0); a0 = fmaf(w.y, h0.y, a0); a0 = fmaf(w.z, h0.z, a0); a0 = fmaf(w.w, h0.w, a0);
      a1 = fmaf(w.x, h1.x, a1); a1 = fmaf(w.y, h1.y, a1); a1 = fmaf(w.z, h1.z, a1); a1 = fmaf(w.w, h1.w, a1);
      a2 = fmaf(w.x, h2.x, a2); a2 = fmaf(w.y, h2.y, a2); a2 = fmaf(w.z, h2.z, a2); a2 = fmaf(w.w, h2.w, a2);
      a3 = fmaf(w.x, h3.x, a3); a3 = fmaf(w.y, h3.y, a3); a3 = fmaf(w.z, h3.z, a3); a3 = fmaf(w.w, h3.w, a3);
    }
#pragma unroll
    for (int m = 1; m < 64; m <<= 1) {
      a0 += __shfl_xor(a0, m, 64);
      a1 += __shfl_xor(a1, m, 64);
      a2 += __shfl_xor(a2, m, 64);
      a3 += __shfl_xor(a3, m, 64);
    }
    if (lane < 4) {
      float val = a0;
      if (lane == 1) val = a1;
      else if (lane == 2) val = a2;
      else if (lane == 3) val = a3;
      fc[(long)(wave * 4 + lane) * Vv + v] = val + out_b[v];
    }
  }
}

extern "C" void kernel_launch(void* const* d_in, const int* in_sizes, int n_in,
                              void* d_out, int out_size, void* d_ws, size_t ws_size,
                              hipStream_t stream) {
  const int*   x       = (const int*)d_in[0];
  const float* dec_hs  = (const float*)d_in[1];
  const float* enc_out = (const float*)d_in[2];
  const float* emb     = (const float*)d_in[3];
  const float* w1_W    = (const float*)d_in[4];
  const float* w1_b    = (const float*)d_in[5];
  const float* w2_W    = (const float*)d_in[6];
  const float* w2_b    = (const float*)d_in[7];
  const float* va_W    = (const float*)d_in[8];
  const float* va_b    = (const float*)d_in[9];
  const float* W_ih    = (const float*)d_in[10];
  // d_in[11] = W_hh: unused (h0 == 0)
  const float* b_ih    = (const float*)d_in[12];
  const float* b_hh    = (const float*)d_in[13];
  const float* out_W   = (const float*)d_in[14];
  const float* out_b   = (const float*)d_in[15];

  char* ws = (char*)d_ws;
  u16*   enc_bf = (u16*)(ws + WS_ENC_BF);
  u16*   w2_bf  = (u16*)(ws + WS_W2_BF);
  float* dpw    = (float*)(ws + WS_DPW);
  float* score  = (float*)(ws + WS_SCORE);
  float* gru_in = (float*)(ws + WS_GRUIN);
  float* gi     = (float*)(ws + WS_GI);

  float* fc       = (float*)d_out;
  float* h_out    = fc + (long)Bb * Vv;      // 804112
  float* attn_out = h_out + Bb * Hh;         // 820496

  k_cvt2<<<4608, 256, 0, stream>>>(enc_out, enc_bf, w2_W, w2_bf);
  k_prep<<<1024, 256, 0, stream>>>(dec_hs, w1_W, w1_b, w2_b, va_b, x, emb, dpw, score, gru_in);
  k_gemm_score<<<dim3(64, 8), 256, 0, stream>>>(enc_bf, w2_bf, dpw, va_W, score);
  k_softmax<<<16, 256, 0, stream>>>(score, attn_out);
  k_context<<<dim3(16, 32), 256, 0, stream>>>(attn_out, enc_out, gru_in);
  k_gi<<<3072, 256, 0, stream>>>(W_ih, gru_in, b_ih, gi);
  k_gates<<<64, 256, 0, stream>>>(gi, b_hh, h_out);
  k_fc<<<(Vv + 127) / 128, 256, 0, stream>>>(out_W, out_b, h_out, fc);
}

// Round 2
// 515.245 us; speedup vs baseline: 1.1336x; 1.1336x over previous
//
#include <hip/hip_runtime.h>
#include <hip/hip_bf16.h>

typedef unsigned short u16;
typedef __attribute__((ext_vector_type(4))) float f32x4;
typedef __attribute__((ext_vector_type(8))) __bf16 bf16x8;
typedef __attribute__((ext_vector_type(8))) unsigned short ushort8;

#define Bb 16
#define Ss 512
#define Hh 1024
#define Ee 256
#define Vv 50257
#define Mm 8192  // Ss*Bb

// ---- workspace layout (bytes) ----
#define WS_ENC_BF   0           // 8192*1024 u16 = 16777216
#define WS_W2_BF    16777216    // 1024*1024 u16 = 2097152
#define WS_DPW      18874368    // 16*1024 f32 (dec_proj + w1_b + w2_b)
#define WS_SCORE    18939904    // 8192 f32
#define WS_GRUIN    18972672    // 16*1280 f32
#define WS_GI       19054592    // 16*3072 f32
// total 19251200 B

__device__ __forceinline__ u16 f2bf(float f) {
  unsigned u = __float_as_uint(f);
  return (u16)((u + 0x7FFFu + ((u >> 16) & 1u)) >> 16);  // RNE
}

__device__ __forceinline__ void gl2lds16(const void* g, void* l) {
  __builtin_amdgcn_global_load_lds((__attribute__((address_space(1))) void*)g,
                                   (__attribute__((address_space(3))) void*)l,
                                   16, 0, 0);
}

// ---------- kernel 0: fp32 -> bf16 convert (enc_output then w2_W) ----------
__global__ __launch_bounds__(256) void k_cvt2(const float* __restrict__ enc, u16* __restrict__ encb,
                                              const float* __restrict__ w2, u16* __restrict__ w2b) {
  int i = blockIdx.x * 256 + threadIdx.x;  // chunk of 8 floats
  const float* src; u16* dst; int j;
  if (i < 1048576) { src = enc; dst = encb; j = i; }
  else             { src = w2;  dst = w2b;  j = i - 1048576; }
  const float4* s4 = (const float4*)src;
  float4 a = s4[j * 2], c = s4[j * 2 + 1];
  ushort8 o;
  o[0] = f2bf(a.x); o[1] = f2bf(a.y); o[2] = f2bf(a.z); o[3] = f2bf(a.w);
  o[4] = f2bf(c.x); o[5] = f2bf(c.y); o[6] = f2bf(c.z); o[7] = f2bf(c.w);
  *(ushort8*)(dst + j * 8) = o;
}

// ---------- kernel 1: dec_proj (+w1_b+w2_b), score init, gru_in init, emb gather ----------
__global__ __launch_bounds__(256) void k_prep(const float* __restrict__ dec_hs, const float* __restrict__ w1_W,
                                              const float* __restrict__ w1_b, const float* __restrict__ w2_b,
                                              const float* __restrict__ va_b, const int* __restrict__ x,
                                              const float* __restrict__ emb, float* __restrict__ dpw,
                                              float* __restrict__ score, float* __restrict__ gru_in) {
  const int n = blockIdx.x, t = threadIdx.x;
  float acc[16];
#pragma unroll
  for (int b = 0; b < 16; ++b) acc[b] = 0.f;
#pragma unroll
  for (int i = 0; i < 4; ++i) {
    int k = t + i * 256;
    float w = w1_W[n * Hh + k];
#pragma unroll
    for (int b = 0; b < 16; ++b) acc[b] = fmaf(w, dec_hs[b * Hh + k], acc[b]);
  }
#pragma unroll
  for (int m = 1; m < 64; m <<= 1)
#pragma unroll
    for (int b = 0; b < 16; ++b) acc[b] += __shfl_xor(acc[b], m, 64);
  __shared__ float red[4][16];
  int wave = t >> 6, lane = t & 63;
  if (lane == 0)
#pragma unroll
    for (int b = 0; b < 16; ++b) red[wave][b] = acc[b];
  __syncthreads();
  if (t < 16)
    dpw[t * Hh + n] = red[0][t] + red[1][t] + red[2][t] + red[3][t] + w1_b[n] + w2_b[n];
  // side work
  int fid = n * 256 + t;
  if (fid < 16384) { int b = fid >> 10, k = fid & 1023; gru_in[b * 1280 + k] = 0.f; }
  int sid = fid - 16384;
  if (sid >= 0 && sid < Mm) score[sid] = va_b[0];
  int eid = fid - 24576;
  if (eid >= 0 && eid < 4096) { int b = eid >> 8, j = eid & 255; gru_in[b * 1280 + 1024 + j] = emb[x[b] * Ee + j]; }
}

// ---------- kernel 2: bf16 MFMA GEMM (enc @ w2^T) + fused tanh*va row-reduce -> score ----------
__global__ __launch_bounds__(256) void k_gemm_score(const u16* __restrict__ A, const u16* __restrict__ Bm,
                                                    const float* __restrict__ dpw, const float* __restrict__ vaW,
                                                    float* __restrict__ score) {
  __shared__ __align__(16) u16 Al[4096];  // 128 rows x 32 k
  __shared__ __align__(16) u16 Bl[4096];
  const int tid = threadIdx.x;
  const int wave = tid >> 6, lane = tid & 63;
  const int quad = lane >> 4, l16 = lane & 15;
  const int m0 = blockIdx.x * 128, n0 = blockIdx.y * 128;
  const int wm = (wave & 1) * 64, wn = (wave >> 1) * 64;

  f32x4 acc[4][4];
#pragma unroll
  for (int i = 0; i < 4; ++i)
#pragma unroll
    for (int j = 0; j < 4; ++j) acc[i][j] = (f32x4){0.f, 0.f, 0.f, 0.f};

  const u16* gA = A + (m0 + (tid >> 2)) * 1024 + (tid & 3) * 8;
  const u16* gB = Bm + (n0 + (tid >> 2)) * 1024 + (tid & 3) * 8;
  u16* lA0 = &Al[(wave * 64) * 8];
  u16* lA1 = &Al[(256 + wave * 64) * 8];
  u16* lB0 = &Bl[(wave * 64) * 8];
  u16* lB1 = &Bl[(256 + wave * 64) * 8];

  for (int kt = 0; kt < 1024; kt += 32) {
    __syncthreads();
    gl2lds16(gA + kt, lA0);
    gl2lds16(gA + 64 * 1024 + kt, lA1);
    gl2lds16(gB + kt, lB0);
    gl2lds16(gB + 64 * 1024 + kt, lB1);
    __syncthreads();
    bf16x8 af[4], bfr[4];
#pragma unroll
    for (int i = 0; i < 4; ++i) {
      af[i]  = *(const bf16x8*)&Al[(wm + i * 16 + l16) * 32 + quad * 8];
      bfr[i] = *(const bf16x8*)&Bl[(wn + i * 16 + l16) * 32 + quad * 8];
    }
#pragma unroll
    for (int i = 0; i < 4; ++i)
#pragma unroll
      for (int j = 0; j < 4; ++j)
        acc[i][j] = __builtin_amdgcn_mfma_f32_16x16x32_bf16(af[i], bfr[j], acc[i][j], 0, 0, 0);
  }

  // epilogue: t = tanh(acc + dpw[b][n]) * va[n]; reduce over n; atomic to score[m]
  __syncthreads();
  float* dpw_t = (float*)Al;  // [16][128] = 8KB
  float* va_t  = (float*)Bl;  // [128]
  for (int idx = tid; idx < 2048; idx += 256) {
    int b = idx >> 7, nn = idx & 127;
    dpw_t[idx] = dpw[b * Hh + n0 + nn];
  }
  if (tid < 128) va_t[tid] = vaW[n0 + tid];
  __syncthreads();

  float rs[4][4];
#pragma unroll
  for (int i = 0; i < 4; ++i)
#pragma unroll
    for (int r = 0; r < 4; ++r) rs[i][r] = 0.f;
#pragma unroll
  for (int i = 0; i < 4; ++i)
#pragma unroll
    for (int j = 0; j < 4; ++j) {
      int nn = wn + j * 16 + l16;
      float va = va_t[nn];
#pragma unroll
      for (int r = 0; r < 4; ++r) {
        float xv = acc[i][j][r] + dpw_t[(quad * 4 + r) * 128 + nn];  // b = quad*4+r
        rs[i][r] += tanhf(xv) * va;
      }
    }
#pragma unroll
  for (int i = 0; i < 4; ++i)
#pragma unroll
    for (int r = 0; r < 4; ++r) {
      float v = rs[i][r];
      v += __shfl_xor(v, 1, 64);
      v += __shfl_xor(v, 2, 64);
      v += __shfl_xor(v, 4, 64);
      v += __shfl_xor(v, 8, 64);
      if (l16 == 0) atomicAdd(&score[m0 + wm + i * 16 + quad * 4 + r], v);
    }
}

// ---------- kernel 3: softmax over S per batch -> attn output ----------
__global__ __launch_bounds__(256) void k_softmax(const float* __restrict__ score, float* __restrict__ attn) {
  const int b = blockIdx.x, t = threadIdx.x;
  __shared__ float red[256];
  float v0 = score[t * Bb + b];
  float v1 = score[(t + 256) * Bb + b];
  red[t] = fmaxf(v0, v1);
  __syncthreads();
  for (int s = 128; s > 0; s >>= 1) { if (t < s) red[t] = fmaxf(red[t], red[t + s]); __syncthreads(); }
  float mx = red[0];
  __syncthreads();
  float e0 = expf(v0 - mx), e1 = expf(v1 - mx);
  red[t] = e0 + e1;
  __syncthreads();
  for (int s = 128; s > 0; s >>= 1) { if (t < s) red[t] += red[t + s]; __syncthreads(); }
  float inv = 1.f / red[0];
  attn[b * Ss + t] = e0 * inv;
  attn[b * Ss + t + 256] = e1 * inv;
}

// ---------- kernel 4: context accumulate into gru_in[:, :1024] ----------
__global__ __launch_bounds__(256) void k_context(const float* __restrict__ attn, const float* __restrict__ enc,
                                                 float* __restrict__ gru_in) {
  const int b = blockIdx.x, sc = blockIdx.y, t = threadIdx.x;
  const int s0 = sc * 16;
  float acc[4] = {0.f, 0.f, 0.f, 0.f};
  for (int s = s0; s < s0 + 16; ++s) {
    float a = attn[b * Ss + s];
    const float* e = enc + (s * Bb + b) * Hh;
#pragma unroll
    for (int hh = 0; hh < 4; ++hh) acc[hh] = fmaf(a, e[t + hh * 256], acc[hh]);
  }
#pragma unroll
  for (int hh = 0; hh < 4; ++hh) atomicAdd(&gru_in[b * 1280 + t + hh * 256], acc[hh]);
}

// ---------- kernel 5: gi = gru_in @ W_ih^T + b_ih ----------
__global__ __launch_bounds__(256) void k_gi(const float* __restrict__ W_ih, const float* __restrict__ gru_in,
                                            const float* __restrict__ b_ih, float* __restrict__ gi) {
  const int n = blockIdx.x, t = threadIdx.x;
  float acc[16];
#pragma unroll
  for (int b = 0; b < 16; ++b) acc[b] = 0.f;
#pragma unroll
  for (int i = 0; i < 5; ++i) {
    int k = t + i * 256;
    float w = W_ih[n * 1280 + k];
#pragma unroll
    for (int b = 0; b < 16; ++b) acc[b] = fmaf(w, gru_in[b * 1280 + k], acc[b]);
  }
#pragma unroll
  for (int m = 1; m < 64; m <<= 1)
#pragma unroll
    for (int b = 0; b < 16; ++b) acc[b] += __shfl_xor(acc[b], m, 64);
  __shared__ float red[4][16];
  int wave = t >> 6, lane = t & 63;
  if (lane == 0)
#pragma unroll
    for (int b = 0; b < 16; ++b) red[wave][b] = acc[b];
  __syncthreads();
  if (t < 16)
    gi[t * 3072 + n] = red[0][t] + red[1][t] + red[2][t] + red[3][t] + b_ih[n];
}

// ---------- kernel 6: GRU gates (h0 = 0 => gh = b_hh; h = (1-z)*n) ----------
__global__ __launch_bounds__(256) void k_gates(const float* __restrict__ gi, const float* __restrict__ b_hh,
                                               float* __restrict__ h_out) {
  int idx = blockIdx.x * 256 + threadIdx.x;  // 16384
  int b = idx >> 10, j = idx & 1023;
  float ir = gi[b * 3072 + j], iz = gi[b * 3072 + 1024 + j], in_ = gi[b * 3072 + 2048 + j];
  float r = 1.f / (1.f + expf(-(ir + b_hh[j])));
  float z = 1.f / (1.f + expf(-(iz + b_hh[1024 + j])));
  float n = tanhf(in_ + r * b_hh[2048 + j]);
  h_out[idx] = (1.f - z) * n;
}

// ---------- kernel 7: fc_out = h @ out_W^T + out_b ----------
// 128 rows/block, 2-way K-split per row, LDS-staged out_W tile via global_load_lds
// with XOR bank swizzle (blk ^ (row&7)) baked into the global-side lane address.
__global__ __launch_bounds__(256) void k_fc(const float* __restrict__ out_W, const float* __restrict__ out_b,
                                            const float* __restrict__ h, float* __restrict__ fc) {
  __shared__ __align__(16) float tile[128 * 128];  // 64 KB
  const int tid = threadIdx.x;
  const int wave = tid >> 6, lane = tid & 63;
  const int khalf = __builtin_amdgcn_readfirstlane(wave >> 1);  // waves 0,1 -> k[0,512); 2,3 -> k[512,1024)
  const int row = (wave & 1) * 64 + lane;                       // 0..127
  const int v0 = blockIdx.x * 128;

  float acc[16];
#pragma unroll
  for (int b = 0; b < 16; ++b) acc[b] = 0.f;

  for (int c = 0; c < 8; ++c) {  // k-chunks of 128
    __syncthreads();
    // wave stages rows [wave*32, wave*32+32): 16 instrs x (2 rows x 512B)
#pragma unroll
    for (int i = 0; i < 16; ++i) {
      int r = wave * 32 + i * 2 + (lane >> 5);
      int gblk = (lane & 31) ^ (r & 7);
      int vrow = v0 + r;
      if (vrow > Vv - 1) vrow = Vv - 1;  // tail clamp (garbage rows never written)
      const float* g = out_W + (long)vrow * Hh + c * 128 + gblk * 4;
      float* l = tile + (wave * 32 + i * 2) * 128;  // wave-uniform LDS base
      gl2lds16(g, l);
    }
    __syncthreads();
    const float* hb = h + c * 128 + khalf * 64;  // wave-uniform -> scalar loads
#pragma unroll
    for (int kk = 0; kk < 64; kk += 4) {
      int blk = khalf * 16 + (kk >> 2);
      int sblk = blk ^ (row & 7);
      float4 w = *(const float4*)&tile[row * 128 + sblk * 4];
#pragma unroll
      for (int b = 0; b < 16; ++b) {
        float4 hv = *(const float4*)&hb[b * Hh + kk];
        acc[b] = fmaf(w.x, hv.x, acc[b]);
        acc[b] = fmaf(w.y, hv.y, acc[b]);
        acc[b] = fmaf(w.z, hv.z, acc[b]);
        acc[b] = fmaf(w.w, hv.w, acc[b]);
      }
    }
  }

  // combine the two K-halves via LDS, write out
  __syncthreads();
  float* red = tile;  // reuse: [128][16]
  if (khalf == 1) {
#pragma unroll
    for (int b = 0; b < 16; ++b) red[row * 16 + b] = acc[b];
  }
  __syncthreads();
  if (khalf == 0) {
    int v = v0 + row;
    if (v < Vv) {
      float ob = out_b[v];
#pragma unroll
      for (int b = 0; b < 16; ++b)
        fc[(long)b * Vv + v] = acc[b] + red[row * 16 + b] + ob;
    }
  }
}

extern "C" void kernel_launch(void* const* d_in, const int* in_sizes, int n_in,
                              void* d_out, int out_size, void* d_ws, size_t ws_size,
                              hipStream_t stream) {
  const int*   x       = (const int*)d_in[0];
  const float* dec_hs  = (const float*)d_in[1];
  const float* enc_out = (const float*)d_in[2];
  const float* emb     = (const float*)d_in[3];
  const float* w1_W    = (const float*)d_in[4];
  const float* w1_b    = (const float*)d_in[5];
  const float* w2_W    = (const float*)d_in[6];
  const float* w2_b    = (const float*)d_in[7];
  const float* va_W    = (const float*)d_in[8];
  const float* va_b    = (const float*)d_in[9];
  const float* W_ih    = (const float*)d_in[10];
  // d_in[11] = W_hh: unused (h0 == 0)
  const float* b_ih    = (const float*)d_in[12];
  const float* b_hh    = (const float*)d_in[13];
  const float* out_W   = (const float*)d_in[14];
  const float* out_b   = (const float*)d_in[15];

  char* ws = (char*)d_ws;
  u16*   enc_bf = (u16*)(ws + WS_ENC_BF);
  u16*   w2_bf  = (u16*)(ws + WS_W2_BF);
  float* dpw    = (float*)(ws + WS_DPW);
  float* score  = (float*)(ws + WS_SCORE);
  float* gru_in = (float*)(ws + WS_GRUIN);
  float* gi     = (float*)(ws + WS_GI);

  float* fc       = (float*)d_out;
  float* h_out    = fc + (long)Bb * Vv;      // 804112
  float* attn_out = h_out + Bb * Hh;         // 820496

  k_cvt2<<<4608, 256, 0, stream>>>(enc_out, enc_bf, w2_W, w2_bf);
  k_prep<<<1024, 256, 0, stream>>>(dec_hs, w1_W, w1_b, w2_b, va_b, x, emb, dpw, score, gru_in);
  k_gemm_score<<<dim3(64, 8), 256, 0, stream>>>(enc_bf, w2_bf, dpw, va_W, score);
  k_softmax<<<16, 256, 0, stream>>>(score, attn_out);
  k_context<<<dim3(16, 32), 256, 0, stream>>>(attn_out, enc_out, gru_in);
  k_gi<<<3072, 256, 0, stream>>>(W_ih, gru_in, b_ih, gi);
  k_gates<<<64, 256, 0, stream>>>(gi, b_hh, h_out);
  k_fc<<<(Vv + 127) / 128, 256, 0, stream>>>(out_W, out_b, h_out, fc);
}

// Round 3
// 450.165 us; speedup vs baseline: 1.2974x; 1.1446x over previous
//
#include <hip/hip_runtime.h>
#include <hip/hip_bf16.h>

typedef unsigned short u16;
typedef __attribute__((ext_vector_type(4))) float f32x4;
typedef __attribute__((ext_vector_type(8))) __bf16 bf16x8;
typedef __attribute__((ext_vector_type(8))) unsigned short ushort8;

#define Bb 16
#define Ss 512
#define Hh 1024
#define Ee 256
#define Vv 50257
#define Mm 8192  // Ss*Bb

// ---- workspace layout (bytes) ----
#define WS_ENC_BF   0           // 8192*1024 u16 = 16777216
#define WS_W2_BF    16777216    // 1024*1024 u16 = 2097152
#define WS_DPW      18874368    // 16*1024 f32 (dec_proj + w1_b + w2_b)
#define WS_SCORE    18939904    // 8192 f32
#define WS_GRUIN    18972672    // 16*1280 f32
#define WS_GI       19054592    // 16*3072 f32
#define WS_HA_HI    19251200    // 16*1024 u16 = 32768 (h bf16-hi, MFMA A-frag layout)
#define WS_HA_LO    19283968    // 16*1024 u16 = 32768 (h bf16-lo)
// total 19316736 B

__device__ __forceinline__ u16 f2bf(float f) {
  unsigned u = __float_as_uint(f);
  return (u16)((u + 0x7FFFu + ((u >> 16) & 1u)) >> 16);  // RNE
}

__device__ __forceinline__ void gl2lds16(const void* g, void* l) {
  __builtin_amdgcn_global_load_lds((__attribute__((address_space(1))) void*)g,
                                   (__attribute__((address_space(3))) void*)l,
                                   16, 0, 0);
}

// ---------- kernel 0: fp32 -> bf16 convert (enc_output then w2_W) ----------
__global__ __launch_bounds__(256) void k_cvt2(const float* __restrict__ enc, u16* __restrict__ encb,
                                              const float* __restrict__ w2, u16* __restrict__ w2b) {
  int i = blockIdx.x * 256 + threadIdx.x;  // chunk of 8 floats
  const float* src; u16* dst; int j;
  if (i < 1048576) { src = enc; dst = encb; j = i; }
  else             { src = w2;  dst = w2b;  j = i - 1048576; }
  const float4* s4 = (const float4*)src;
  float4 a = s4[j * 2], c = s4[j * 2 + 1];
  ushort8 o;
  o[0] = f2bf(a.x); o[1] = f2bf(a.y); o[2] = f2bf(a.z); o[3] = f2bf(a.w);
  o[4] = f2bf(c.x); o[5] = f2bf(c.y); o[6] = f2bf(c.z); o[7] = f2bf(c.w);
  *(ushort8*)(dst + j * 8) = o;
}

// ---------- kernel 1: dec_proj (+w1_b+w2_b), score init, gru_in init, emb gather ----------
__global__ __launch_bounds__(256) void k_prep(const float* __restrict__ dec_hs, const float* __restrict__ w1_W,
                                              const float* __restrict__ w1_b, const float* __restrict__ w2_b,
                                              const float* __restrict__ va_b, const int* __restrict__ x,
                                              const float* __restrict__ emb, float* __restrict__ dpw,
                                              float* __restrict__ score, float* __restrict__ gru_in) {
  const int n = blockIdx.x, t = threadIdx.x;
  float acc[16];
#pragma unroll
  for (int b = 0; b < 16; ++b) acc[b] = 0.f;
#pragma unroll
  for (int i = 0; i < 4; ++i) {
    int k = t + i * 256;
    float w = w1_W[n * Hh + k];
#pragma unroll
    for (int b = 0; b < 16; ++b) acc[b] = fmaf(w, dec_hs[b * Hh + k], acc[b]);
  }
#pragma unroll
  for (int m = 1; m < 64; m <<= 1)
#pragma unroll
    for (int b = 0; b < 16; ++b) acc[b] += __shfl_xor(acc[b], m, 64);
  __shared__ float red[4][16];
  int wave = t >> 6, lane = t & 63;
  if (lane == 0)
#pragma unroll
    for (int b = 0; b < 16; ++b) red[wave][b] = acc[b];
  __syncthreads();
  if (t < 16)
    dpw[t * Hh + n] = red[0][t] + red[1][t] + red[2][t] + red[3][t] + w1_b[n] + w2_b[n];
  // side work
  int fid = n * 256 + t;
  if (fid < 16384) { int b = fid >> 10, k = fid & 1023; gru_in[b * 1280 + k] = 0.f; }
  int sid = fid - 16384;
  if (sid >= 0 && sid < Mm) score[sid] = va_b[0];
  int eid = fid - 24576;
  if (eid >= 0 && eid < 4096) { int b = eid >> 8, j = eid & 255; gru_in[b * 1280 + 1024 + j] = emb[x[b] * Ee + j]; }
}

// ---------- kernel 2: bf16 MFMA GEMM (enc @ w2^T) + fused tanh*va row-reduce -> score ----------
__global__ __launch_bounds__(256) void k_gemm_score(const u16* __restrict__ A, const u16* __restrict__ Bm,
                                                    const float* __restrict__ dpw, const float* __restrict__ vaW,
                                                    float* __restrict__ score) {
  __shared__ __align__(16) u16 Al[4096];  // 128 rows x 32 k
  __shared__ __align__(16) u16 Bl[4096];
  const int tid = threadIdx.x;
  const int wave = tid >> 6, lane = tid & 63;
  const int quad = lane >> 4, l16 = lane & 15;
  const int m0 = blockIdx.x * 128, n0 = blockIdx.y * 128;
  const int wm = (wave & 1) * 64, wn = (wave >> 1) * 64;

  f32x4 acc[4][4];
#pragma unroll
  for (int i = 0; i < 4; ++i)
#pragma unroll
    for (int j = 0; j < 4; ++j) acc[i][j] = (f32x4){0.f, 0.f, 0.f, 0.f};

  const u16* gA = A + (m0 + (tid >> 2)) * 1024 + (tid & 3) * 8;
  const u16* gB = Bm + (n0 + (tid >> 2)) * 1024 + (tid & 3) * 8;
  u16* lA0 = &Al[(wave * 64) * 8];
  u16* lA1 = &Al[(256 + wave * 64) * 8];
  u16* lB0 = &Bl[(wave * 64) * 8];
  u16* lB1 = &Bl[(256 + wave * 64) * 8];

  for (int kt = 0; kt < 1024; kt += 32) {
    __syncthreads();
    gl2lds16(gA + kt, lA0);
    gl2lds16(gA + 64 * 1024 + kt, lA1);
    gl2lds16(gB + kt, lB0);
    gl2lds16(gB + 64 * 1024 + kt, lB1);
    __syncthreads();
    bf16x8 af[4], bfr[4];
#pragma unroll
    for (int i = 0; i < 4; ++i) {
      af[i]  = *(const bf16x8*)&Al[(wm + i * 16 + l16) * 32 + quad * 8];
      bfr[i] = *(const bf16x8*)&Bl[(wn + i * 16 + l16) * 32 + quad * 8];
    }
#pragma unroll
    for (int i = 0; i < 4; ++i)
#pragma unroll
      for (int j = 0; j < 4; ++j)
        acc[i][j] = __builtin_amdgcn_mfma_f32_16x16x32_bf16(af[i], bfr[j], acc[i][j], 0, 0, 0);
  }

  // epilogue: t = tanh(acc + dpw[b][n]) * va[n]; reduce over n; atomic to score[m]
  __syncthreads();
  float* dpw_t = (float*)Al;  // [16][128] = 8KB
  float* va_t  = (float*)Bl;  // [128]
  for (int idx = tid; idx < 2048; idx += 256) {
    int b = idx >> 7, nn = idx & 127;
    dpw_t[idx] = dpw[b * Hh + n0 + nn];
  }
  if (tid < 128) va_t[tid] = vaW[n0 + tid];
  __syncthreads();

  float rs[4][4];
#pragma unroll
  for (int i = 0; i < 4; ++i)
#pragma unroll
    for (int r = 0; r < 4; ++r) rs[i][r] = 0.f;
#pragma unroll
  for (int i = 0; i < 4; ++i)
#pragma unroll
    for (int j = 0; j < 4; ++j) {
      int nn = wn + j * 16 + l16;
      float va = va_t[nn];
#pragma unroll
      for (int r = 0; r < 4; ++r) {
        float xv = acc[i][j][r] + dpw_t[(quad * 4 + r) * 128 + nn];  // b = quad*4+r
        rs[i][r] += tanhf(xv) * va;
      }
    }
#pragma unroll
  for (int i = 0; i < 4; ++i)
#pragma unroll
    for (int r = 0; r < 4; ++r) {
      float v = rs[i][r];
      v += __shfl_xor(v, 1, 64);
      v += __shfl_xor(v, 2, 64);
      v += __shfl_xor(v, 4, 64);
      v += __shfl_xor(v, 8, 64);
      if (l16 == 0) atomicAdd(&score[m0 + wm + i * 16 + quad * 4 + r], v);
    }
}

// ---------- kernel 3: softmax over S per batch -> attn output ----------
__global__ __launch_bounds__(256) void k_softmax(const float* __restrict__ score, float* __restrict__ attn) {
  const int b = blockIdx.x, t = threadIdx.x;
  __shared__ float red[256];
  float v0 = score[t * Bb + b];
  float v1 = score[(t + 256) * Bb + b];
  red[t] = fmaxf(v0, v1);
  __syncthreads();
  for (int s = 128; s > 0; s >>= 1) { if (t < s) red[t] = fmaxf(red[t], red[t + s]); __syncthreads(); }
  float mx = red[0];
  __syncthreads();
  float e0 = expf(v0 - mx), e1 = expf(v1 - mx);
  red[t] = e0 + e1;
  __syncthreads();
  for (int s = 128; s > 0; s >>= 1) { if (t < s) red[t] += red[t + s]; __syncthreads(); }
  float inv = 1.f / red[0];
  attn[b * Ss + t] = e0 * inv;
  attn[b * Ss + t + 256] = e1 * inv;
}

// ---------- kernel 4: context accumulate into gru_in[:, :1024] ----------
__global__ __launch_bounds__(256) void k_context(const float* __restrict__ attn, const float* __restrict__ enc,
                                                 float* __restrict__ gru_in) {
  const int b = blockIdx.x, sc = blockIdx.y, t = threadIdx.x;
  const int s0 = sc * 16;
  float acc[4] = {0.f, 0.f, 0.f, 0.f};
  for (int s = s0; s < s0 + 16; ++s) {
    float a = attn[b * Ss + s];
    const float* e = enc + (s * Bb + b) * Hh;
#pragma unroll
    for (int hh = 0; hh < 4; ++hh) acc[hh] = fmaf(a, e[t + hh * 256], acc[hh]);
  }
#pragma unroll
  for (int hh = 0; hh < 4; ++hh) atomicAdd(&gru_in[b * 1280 + t + hh * 256], acc[hh]);
}

// ---------- kernel 5: gi = gru_in @ W_ih^T + b_ih ----------
__global__ __launch_bounds__(256) void k_gi(const float* __restrict__ W_ih, const float* __restrict__ gru_in,
                                            const float* __restrict__ b_ih, float* __restrict__ gi) {
  const int n = blockIdx.x, t = threadIdx.x;
  float acc[16];
#pragma unroll
  for (int b = 0; b < 16; ++b) acc[b] = 0.f;
#pragma unroll
  for (int i = 0; i < 5; ++i) {
    int k = t + i * 256;
    float w = W_ih[n * 1280 + k];
#pragma unroll
    for (int b = 0; b < 16; ++b) acc[b] = fmaf(w, gru_in[b * 1280 + k], acc[b]);
  }
#pragma unroll
  for (int m = 1; m < 64; m <<= 1)
#pragma unroll
    for (int b = 0; b < 16; ++b) acc[b] += __shfl_xor(acc[b], m, 64);
  __shared__ float red[4][16];
  int wave = t >> 6, lane = t & 63;
  if (lane == 0)
#pragma unroll
    for (int b = 0; b < 16; ++b) red[wave][b] = acc[b];
  __syncthreads();
  if (t < 16)
    gi[t * 3072 + n] = red[0][t] + red[1][t] + red[2][t] + red[3][t] + b_ih[n];
}

// ---------- kernel 6: GRU gates; writes h fp32 (output) + bf16 hi/lo split in MFMA A-frag layout ----------
__global__ __launch_bounds__(256) void k_gates(const float* __restrict__ gi, const float* __restrict__ b_hh,
                                               float* __restrict__ h_out, u16* __restrict__ hA_hi,
                                               u16* __restrict__ hA_lo) {
  int idx = blockIdx.x * 256 + threadIdx.x;  // 16384
  int b = idx >> 10, j = idx & 1023;
  float ir = gi[b * 3072 + j], iz = gi[b * 3072 + 1024 + j], in_ = gi[b * 3072 + 2048 + j];
  float r = 1.f / (1.f + expf(-(ir + b_hh[j])));
  float z = 1.f / (1.f + expf(-(iz + b_hh[1024 + j])));
  float n = tanhf(in_ + r * b_hh[2048 + j]);
  float hv = (1.f - z) * n;
  h_out[idx] = hv;
  // exact-ish split: hv ~= hi + lo in bf16 pair (residual ~2^-17 |hv|)
  u16 hi = f2bf(hv);
  float hi_f = __uint_as_float((unsigned)hi << 16);
  u16 lo = f2bf(hv - hi_f);
  // A-frag layout: group g = j>>3 ; [g][b][j&7]
  int g = j >> 3, jj = j & 7;
  hA_hi[g * 128 + b * 8 + jj] = hi;
  hA_lo[g * 128 + b * 8 + jj] = lo;
}

// ---------- kernel 7: fc_out = h @ out_W^T + out_b via MFMA ----------
// W stays fp32 in HBM; staged 128 rows x 128 k into LDS (XOR granule swizzle),
// converted to bf16 in-register. h enters as pre-packed bf16 hi/lo A-fragments
// (one coalesced 1KB wave load per fragment, L1-hot).
__global__ __launch_bounds__(256) void k_fc(const float* __restrict__ out_W, const float* __restrict__ out_b,
                                            const u16* __restrict__ hA_hi, const u16* __restrict__ hA_lo,
                                            float* __restrict__ fc) {
  __shared__ __align__(16) float tile[128 * 128];  // 64 KB
  const int tid = threadIdx.x;
  const int wave = tid >> 6, lane = tid & 63;
  const int quad = lane >> 4, l16 = lane & 15;
  const int v0 = blockIdx.x * 128;

  f32x4 acc[2];
  acc[0] = (f32x4){0.f, 0.f, 0.f, 0.f};
  acc[1] = (f32x4){0.f, 0.f, 0.f, 0.f};

  for (int c = 0; c < 8; ++c) {  // K-chunks of 128
    __syncthreads();
    // wave stages rows [wave*32, wave*32+32): 16 instrs x (2 rows x 512B), XOR swizzle on global side
#pragma unroll
    for (int i = 0; i < 16; ++i) {
      int r = wave * 32 + i * 2 + (lane >> 5);
      int gg = (lane & 31) ^ (r & 7);  // 16B granule permute
      int vrow = v0 + r;
      if (vrow > Vv - 1) vrow = Vv - 1;  // tail clamp (clamped rows never stored)
      const float* g = out_W + (long)vrow * Hh + c * 128 + gg * 4;
      float* l = tile + (wave * 32 + i * 2) * 128;  // wave-uniform LDS base
      gl2lds16(g, l);
    }
    __syncthreads();
#pragma unroll
    for (int s = 0; s < 4; ++s) {  // 4 MFMA k-steps of 32 within the chunk
      // A fragments: coalesced 1KB wave loads, identical for all waves (L1 broadcast)
      int gbase = c * 16 + s * 4 + quad;  // k-group of 8
      bf16x8 a_hi = *(const bf16x8*)(hA_hi + gbase * 128 + l16 * 8);
      bf16x8 a_lo = *(const bf16x8*)(hA_lo + gbase * 128 + l16 * 8);
#pragma unroll
      for (int t = 0; t < 2; ++t) {  // two 16-row n-tiles per wave
        int vl = wave * 32 + t * 16 + l16;  // row within tile
        int m0 = s * 8 + quad * 2;          // logical 16B granule of k-window start
        int p0 = m0 ^ (vl & 7), p1 = (m0 + 1) ^ (vl & 7);
        const float* rowp = tile + vl * 128;
        f32x4 w0 = *(const f32x4*)(rowp + p0 * 4);
        f32x4 w1 = *(const f32x4*)(rowp + p1 * 4);
        union { ushort8 u; bf16x8 b; } bu;
        bu.u[0] = f2bf(w0[0]); bu.u[1] = f2bf(w0[1]); bu.u[2] = f2bf(w0[2]); bu.u[3] = f2bf(w0[3]);
        bu.u[4] = f2bf(w1[0]); bu.u[5] = f2bf(w1[1]); bu.u[6] = f2bf(w1[2]); bu.u[7] = f2bf(w1[3]);
        acc[t] = __builtin_amdgcn_mfma_f32_16x16x32_bf16(a_hi, bu.b, acc[t], 0, 0, 0);
        acc[t] = __builtin_amdgcn_mfma_f32_16x16x32_bf16(a_lo, bu.b, acc[t], 0, 0, 0);
      }
    }
  }

  // epilogue: D[batch = quad*4+r][v = v0 + wave*32 + t*16 + l16]
#pragma unroll
  for (int t = 0; t < 2; ++t) {
    int v = v0 + wave * 32 + t * 16 + l16;
    if (v < Vv) {
      float ob = out_b[v];
#pragma unroll
      for (int r = 0; r < 4; ++r)
        fc[(long)(quad * 4 + r) * Vv + v] = acc[t][r] + ob;
    }
  }
}

extern "C" void kernel_launch(void* const* d_in, const int* in_sizes, int n_in,
                              void* d_out, int out_size, void* d_ws, size_t ws_size,
                              hipStream_t stream) {
  const int*   x       = (const int*)d_in[0];
  const float* dec_hs  = (const float*)d_in[1];
  const float* enc_out = (const float*)d_in[2];
  const float* emb     = (const float*)d_in[3];
  const float* w1_W    = (const float*)d_in[4];
  const float* w1_b    = (const float*)d_in[5];
  const float* w2_W    = (const float*)d_in[6];
  const float* w2_b    = (const float*)d_in[7];
  const float* va_W    = (const float*)d_in[8];
  const float* va_b    = (const float*)d_in[9];
  const float* W_ih    = (const float*)d_in[10];
  // d_in[11] = W_hh: unused (h0 == 0)
  const float* b_ih    = (const float*)d_in[12];
  const float* b_hh    = (const float*)d_in[13];
  const float* out_W   = (const float*)d_in[14];
  const float* out_b   = (const float*)d_in[15];

  char* ws = (char*)d_ws;
  u16*   enc_bf = (u16*)(ws + WS_ENC_BF);
  u16*   w2_bf  = (u16*)(ws + WS_W2_BF);
  float* dpw    = (float*)(ws + WS_DPW);
  float* score  = (float*)(ws + WS_SCORE);
  float* gru_in = (float*)(ws + WS_GRUIN);
  float* gi     = (float*)(ws + WS_GI);
  u16*   hA_hi  = (u16*)(ws + WS_HA_HI);
  u16*   hA_lo  = (u16*)(ws + WS_HA_LO);

  float* fc       = (float*)d_out;
  float* h_out    = fc + (long)Bb * Vv;      // 804112
  float* attn_out = h_out + Bb * Hh;         // 820496

  k_cvt2<<<4608, 256, 0, stream>>>(enc_out, enc_bf, w2_W, w2_bf);
  k_prep<<<1024, 256, 0, stream>>>(dec_hs, w1_W, w1_b, w2_b, va_b, x, emb, dpw, score, gru_in);
  k_gemm_score<<<dim3(64, 8), 256, 0, stream>>>(enc_bf, w2_bf, dpw, va_W, score);
  k_softmax<<<16, 256, 0, stream>>>(score, attn_out);
  k_context<<<dim3(16, 32), 256, 0, stream>>>(attn_out, enc_out, gru_in);
  k_gi<<<3072, 256, 0, stream>>>(W_ih, gru_in, b_ih, gi);
  k_gates<<<64, 256, 0, stream>>>(gi, b_hh, h_out, hA_hi, hA_lo);
  k_fc<<<(Vv + 127) / 128, 256, 0, stream>>>(out_W, out_b, hA_hi, hA_lo, fc);
}

// Round 4
// 447.460 us; speedup vs baseline: 1.3053x; 1.0060x over previous
//
#include <hip/hip_runtime.h>
#include <hip/hip_bf16.h>

typedef unsigned short u16;
typedef __attribute__((ext_vector_type(4))) float f32x4;
typedef __attribute__((ext_vector_type(8))) __bf16 bf16x8;
typedef __attribute__((ext_vector_type(8))) unsigned short ushort8;

#define Bb 16
#define Ss 512
#define Hh 1024
#define Ee 256
#define Vv 50257
#define Mm 8192  // Ss*Bb

// ---- workspace layout (bytes) ----
#define WS_ENC_BF   0           // 8192*1024 u16 = 16777216
#define WS_W2_BF    16777216    // 1024*1024 u16 = 2097152
#define WS_DPW      18874368    // 16*1024 f32 (dec_proj + w1_b + w2_b)
#define WS_SCORE    18939904    // 8192 f32
#define WS_GRUIN    18972672    // 16*1280 f32
#define WS_GI       19054592    // 16*3072 f32
#define WS_HA_HI    19251200    // 16*1024 u16 = 32768 (h bf16-hi, MFMA A-frag layout)
#define WS_HA_LO    19283968    // 16*1024 u16 = 32768 (h bf16-lo)
// total 19316736 B

__device__ __forceinline__ u16 f2bf(float f) {
  unsigned u = __float_as_uint(f);
  return (u16)((u + 0x7FFFu + ((u >> 16) & 1u)) >> 16);  // RNE
}

__device__ __forceinline__ void gl2lds16(const void* g, void* l) {
  __builtin_amdgcn_global_load_lds((__attribute__((address_space(1))) void*)g,
                                   (__attribute__((address_space(3))) void*)l,
                                   16, 0, 0);
}

// ---------- kernel 0: fp32 -> bf16 convert (enc_output then w2_W) ----------
__global__ __launch_bounds__(256) void k_cvt2(const float* __restrict__ enc, u16* __restrict__ encb,
                                              const float* __restrict__ w2, u16* __restrict__ w2b) {
  int i = blockIdx.x * 256 + threadIdx.x;  // chunk of 8 floats
  const float* src; u16* dst; int j;
  if (i < 1048576) { src = enc; dst = encb; j = i; }
  else             { src = w2;  dst = w2b;  j = i - 1048576; }
  const float4* s4 = (const float4*)src;
  float4 a = s4[j * 2], c = s4[j * 2 + 1];
  ushort8 o;
  o[0] = f2bf(a.x); o[1] = f2bf(a.y); o[2] = f2bf(a.z); o[3] = f2bf(a.w);
  o[4] = f2bf(c.x); o[5] = f2bf(c.y); o[6] = f2bf(c.z); o[7] = f2bf(c.w);
  *(ushort8*)(dst + j * 8) = o;
}

// ---------- kernel 1: dec_proj (+w1_b+w2_b), score init, gru_in init, emb gather ----------
__global__ __launch_bounds__(256) void k_prep(const float* __restrict__ dec_hs, const float* __restrict__ w1_W,
                                              const float* __restrict__ w1_b, const float* __restrict__ w2_b,
                                              const float* __restrict__ va_b, const int* __restrict__ x,
                                              const float* __restrict__ emb, float* __restrict__ dpw,
                                              float* __restrict__ score, float* __restrict__ gru_in) {
  const int n = blockIdx.x, t = threadIdx.x;
  float acc[16];
#pragma unroll
  for (int b = 0; b < 16; ++b) acc[b] = 0.f;
#pragma unroll
  for (int i = 0; i < 4; ++i) {
    int k = t + i * 256;
    float w = w1_W[n * Hh + k];
#pragma unroll
    for (int b = 0; b < 16; ++b) acc[b] = fmaf(w, dec_hs[b * Hh + k], acc[b]);
  }
#pragma unroll
  for (int m = 1; m < 64; m <<= 1)
#pragma unroll
    for (int b = 0; b < 16; ++b) acc[b] += __shfl_xor(acc[b], m, 64);
  __shared__ float red[4][16];
  int wave = t >> 6, lane = t & 63;
  if (lane == 0)
#pragma unroll
    for (int b = 0; b < 16; ++b) red[wave][b] = acc[b];
  __syncthreads();
  if (t < 16)
    dpw[t * Hh + n] = red[0][t] + red[1][t] + red[2][t] + red[3][t] + w1_b[n] + w2_b[n];
  // side work
  int fid = n * 256 + t;
  if (fid < 16384) { int b = fid >> 10, k = fid & 1023; gru_in[b * 1280 + k] = 0.f; }
  int sid = fid - 16384;
  if (sid >= 0 && sid < Mm) score[sid] = va_b[0];
  int eid = fid - 24576;
  if (eid >= 0 && eid < 4096) { int b = eid >> 8, j = eid & 255; gru_in[b * 1280 + 1024 + j] = emb[x[b] * Ee + j]; }
}

// ---------- kernel 2: bf16 MFMA GEMM (enc @ w2^T) + fused tanh*va row-reduce -> score ----------
__global__ __launch_bounds__(256) void k_gemm_score(const u16* __restrict__ A, const u16* __restrict__ Bm,
                                                    const float* __restrict__ dpw, const float* __restrict__ vaW,
                                                    float* __restrict__ score) {
  __shared__ __align__(16) u16 Al[4096];  // 128 rows x 32 k
  __shared__ __align__(16) u16 Bl[4096];
  const int tid = threadIdx.x;
  const int wave = tid >> 6, lane = tid & 63;
  const int quad = lane >> 4, l16 = lane & 15;
  const int m0 = blockIdx.x * 128, n0 = blockIdx.y * 128;
  const int wm = (wave & 1) * 64, wn = (wave >> 1) * 64;

  f32x4 acc[4][4];
#pragma unroll
  for (int i = 0; i < 4; ++i)
#pragma unroll
    for (int j = 0; j < 4; ++j) acc[i][j] = (f32x4){0.f, 0.f, 0.f, 0.f};

  const u16* gA = A + (m0 + (tid >> 2)) * 1024 + (tid & 3) * 8;
  const u16* gB = Bm + (n0 + (tid >> 2)) * 1024 + (tid & 3) * 8;
  u16* lA0 = &Al[(wave * 64) * 8];
  u16* lA1 = &Al[(256 + wave * 64) * 8];
  u16* lB0 = &Bl[(wave * 64) * 8];
  u16* lB1 = &Bl[(256 + wave * 64) * 8];

  for (int kt = 0; kt < 1024; kt += 32) {
    __syncthreads();
    gl2lds16(gA + kt, lA0);
    gl2lds16(gA + 64 * 1024 + kt, lA1);
    gl2lds16(gB + kt, lB0);
    gl2lds16(gB + 64 * 1024 + kt, lB1);
    __syncthreads();
    bf16x8 af[4], bfr[4];
#pragma unroll
    for (int i = 0; i < 4; ++i) {
      af[i]  = *(const bf16x8*)&Al[(wm + i * 16 + l16) * 32 + quad * 8];
      bfr[i] = *(const bf16x8*)&Bl[(wn + i * 16 + l16) * 32 + quad * 8];
    }
#pragma unroll
    for (int i = 0; i < 4; ++i)
#pragma unroll
      for (int j = 0; j < 4; ++j)
        acc[i][j] = __builtin_amdgcn_mfma_f32_16x16x32_bf16(af[i], bfr[j], acc[i][j], 0, 0, 0);
  }

  // epilogue: t = tanh(acc + dpw[b][n]) * va[n]; reduce over n; atomic to score[m]
  __syncthreads();
  float* dpw_t = (float*)Al;  // [16][128] = 8KB
  float* va_t  = (float*)Bl;  // [128]
  for (int idx = tid; idx < 2048; idx += 256) {
    int b = idx >> 7, nn = idx & 127;
    dpw_t[idx] = dpw[b * Hh + n0 + nn];
  }
  if (tid < 128) va_t[tid] = vaW[n0 + tid];
  __syncthreads();

  float rs[4][4];
#pragma unroll
  for (int i = 0; i < 4; ++i)
#pragma unroll
    for (int r = 0; r < 4; ++r) rs[i][r] = 0.f;
#pragma unroll
  for (int i = 0; i < 4; ++i)
#pragma unroll
    for (int j = 0; j < 4; ++j) {
      int nn = wn + j * 16 + l16;
      float va = va_t[nn];
#pragma unroll
      for (int r = 0; r < 4; ++r) {
        float xv = acc[i][j][r] + dpw_t[(quad * 4 + r) * 128 + nn];  // b = quad*4+r
        rs[i][r] += tanhf(xv) * va;
      }
    }
#pragma unroll
  for (int i = 0; i < 4; ++i)
#pragma unroll
    for (int r = 0; r < 4; ++r) {
      float v = rs[i][r];
      v += __shfl_xor(v, 1, 64);
      v += __shfl_xor(v, 2, 64);
      v += __shfl_xor(v, 4, 64);
      v += __shfl_xor(v, 8, 64);
      if (l16 == 0) atomicAdd(&score[m0 + wm + i * 16 + quad * 4 + r], v);
    }
}

// ---------- kernel 3: softmax over S per batch -> attn output ----------
__global__ __launch_bounds__(256) void k_softmax(const float* __restrict__ score, float* __restrict__ attn) {
  const int b = blockIdx.x, t = threadIdx.x;
  __shared__ float red[256];
  float v0 = score[t * Bb + b];
  float v1 = score[(t + 256) * Bb + b];
  red[t] = fmaxf(v0, v1);
  __syncthreads();
  for (int s = 128; s > 0; s >>= 1) { if (t < s) red[t] = fmaxf(red[t], red[t + s]); __syncthreads(); }
  float mx = red[0];
  __syncthreads();
  float e0 = expf(v0 - mx), e1 = expf(v1 - mx);
  red[t] = e0 + e1;
  __syncthreads();
  for (int s = 128; s > 0; s >>= 1) { if (t < s) red[t] += red[t + s]; __syncthreads(); }
  float inv = 1.f / red[0];
  attn[b * Ss + t] = e0 * inv;
  attn[b * Ss + t + 256] = e1 * inv;
}

// ---------- kernel 4: context accumulate into gru_in[:, :1024] ----------
__global__ __launch_bounds__(256) void k_context(const float* __restrict__ attn, const float* __restrict__ enc,
                                                 float* __restrict__ gru_in) {
  const int b = blockIdx.x, sc = blockIdx.y, t = threadIdx.x;
  const int s0 = sc * 16;
  float acc[4] = {0.f, 0.f, 0.f, 0.f};
  for (int s = s0; s < s0 + 16; ++s) {
    float a = attn[b * Ss + s];
    const float* e = enc + (s * Bb + b) * Hh;
#pragma unroll
    for (int hh = 0; hh < 4; ++hh) acc[hh] = fmaf(a, e[t + hh * 256], acc[hh]);
  }
#pragma unroll
  for (int hh = 0; hh < 4; ++hh) atomicAdd(&gru_in[b * 1280 + t + hh * 256], acc[hh]);
}

// ---------- kernel 5: gi = gru_in @ W_ih^T + b_ih ----------
__global__ __launch_bounds__(256) void k_gi(const float* __restrict__ W_ih, const float* __restrict__ gru_in,
                                            const float* __restrict__ b_ih, float* __restrict__ gi) {
  const int n = blockIdx.x, t = threadIdx.x;
  float acc[16];
#pragma unroll
  for (int b = 0; b < 16; ++b) acc[b] = 0.f;
#pragma unroll
  for (int i = 0; i < 5; ++i) {
    int k = t + i * 256;
    float w = W_ih[n * 1280 + k];
#pragma unroll
    for (int b = 0; b < 16; ++b) acc[b] = fmaf(w, gru_in[b * 1280 + k], acc[b]);
  }
#pragma unroll
  for (int m = 1; m < 64; m <<= 1)
#pragma unroll
    for (int b = 0; b < 16; ++b) acc[b] += __shfl_xor(acc[b], m, 64);
  __shared__ float red[4][16];
  int wave = t >> 6, lane = t & 63;
  if (lane == 0)
#pragma unroll
    for (int b = 0; b < 16; ++b) red[wave][b] = acc[b];
  __syncthreads();
  if (t < 16)
    gi[t * 3072 + n] = red[0][t] + red[1][t] + red[2][t] + red[3][t] + b_ih[n];
}

// ---------- kernel 6: GRU gates; writes h fp32 (output) + bf16 hi/lo split in MFMA A-frag layout ----------
__global__ __launch_bounds__(256) void k_gates(const float* __restrict__ gi, const float* __restrict__ b_hh,
                                               float* __restrict__ h_out, u16* __restrict__ hA_hi,
                                               u16* __restrict__ hA_lo) {
  int idx = blockIdx.x * 256 + threadIdx.x;  // 16384
  int b = idx >> 10, j = idx & 1023;
  float ir = gi[b * 3072 + j], iz = gi[b * 3072 + 1024 + j], in_ = gi[b * 3072 + 2048 + j];
  float r = 1.f / (1.f + expf(-(ir + b_hh[j])));
  float z = 1.f / (1.f + expf(-(iz + b_hh[1024 + j])));
  float n = tanhf(in_ + r * b_hh[2048 + j]);
  float hv = (1.f - z) * n;
  h_out[idx] = hv;
  // exact-ish split: hv ~= hi + lo in bf16 pair (residual ~2^-17 |hv|)
  u16 hi = f2bf(hv);
  float hi_f = __uint_as_float((unsigned)hi << 16);
  u16 lo = f2bf(hv - hi_f);
  // A-frag layout: group g = j>>3 ; [g][b][j&7]
  int g = j >> 3, jj = j & 7;
  hA_hi[g * 128 + b * 8 + jj] = hi;
  hA_lo[g * 128 + b * 8 + jj] = lo;
}

// ---------- kernel 7: fc_out = h @ out_W^T + out_b via MFMA, LDS-free ----------
// B-fragment (B[k=quad*8+j][n=l16]) maps to 8 contiguous fp32 of out_W row
// (v0+w*16+l16) -> direct global_load_dwordx4 pairs, 16 rows x 128B fully-used
// lines per wave-load. No LDS, no barriers; ~3 blocks/CU. A (h hi/lo, 32KB,
// same addresses for all blocks) streams from L1. Two independent MFMA chains.
__global__ __launch_bounds__(256) void k_fc(const float* __restrict__ out_W, const float* __restrict__ out_b,
                                            const u16* __restrict__ hA_hi, const u16* __restrict__ hA_lo,
                                            float* __restrict__ fc) {
  const int tid = threadIdx.x;
  const int wave = tid >> 6, lane = tid & 63;
  const int quad = lane >> 4, l16 = lane & 15;
  const int v = blockIdx.x * 64 + wave * 16 + l16;
  const int vr = v < Vv ? v : (Vv - 1);  // tail clamp (clamped rows never stored)
  const float* wrow = out_W + (long)vr * Hh + quad * 8;
  const u16* pa_hi = hA_hi + quad * 128 + l16 * 8;
  const u16* pa_lo = hA_lo + quad * 128 + l16 * 8;

  f32x4 acc0 = (f32x4){0.f, 0.f, 0.f, 0.f};
  f32x4 acc1 = (f32x4){0.f, 0.f, 0.f, 0.f};

#pragma unroll 4
  for (int kw = 0; kw < 32; ++kw) {  // K-windows of 32
    bf16x8 a_hi = *(const bf16x8*)(pa_hi + kw * 512);  // (kw*4+quad)*128 + l16*8
    bf16x8 a_lo = *(const bf16x8*)(pa_lo + kw * 512);
    f32x4 w0 = *(const f32x4*)(wrow + kw * 32);
    f32x4 w1 = *(const f32x4*)(wrow + kw * 32 + 4);
    union { ushort8 u; bf16x8 b; } bu;
    bu.u[0] = f2bf(w0[0]); bu.u[1] = f2bf(w0[1]); bu.u[2] = f2bf(w0[2]); bu.u[3] = f2bf(w0[3]);
    bu.u[4] = f2bf(w1[0]); bu.u[5] = f2bf(w1[1]); bu.u[6] = f2bf(w1[2]); bu.u[7] = f2bf(w1[3]);
    acc0 = __builtin_amdgcn_mfma_f32_16x16x32_bf16(a_hi, bu.b, acc0, 0, 0, 0);
    acc1 = __builtin_amdgcn_mfma_f32_16x16x32_bf16(a_lo, bu.b, acc1, 0, 0, 0);
  }

  // D: col = l16 -> vocab v, row = quad*4+r -> batch
  if (v < Vv) {
    float ob = out_b[v];
#pragma unroll
    for (int r = 0; r < 4; ++r)
      fc[(long)(quad * 4 + r) * Vv + v] = acc0[r] + acc1[r] + ob;
  }
}

extern "C" void kernel_launch(void* const* d_in, const int* in_sizes, int n_in,
                              void* d_out, int out_size, void* d_ws, size_t ws_size,
                              hipStream_t stream) {
  const int*   x       = (const int*)d_in[0];
  const float* dec_hs  = (const float*)d_in[1];
  const float* enc_out = (const float*)d_in[2];
  const float* emb     = (const float*)d_in[3];
  const float* w1_W    = (const float*)d_in[4];
  const float* w1_b    = (const float*)d_in[5];
  const float* w2_W    = (const float*)d_in[6];
  const float* w2_b    = (const float*)d_in[7];
  const float* va_W    = (const float*)d_in[8];
  const float* va_b    = (const float*)d_in[9];
  const float* W_ih    = (const float*)d_in[10];
  // d_in[11] = W_hh: unused (h0 == 0)
  const float* b_ih    = (const float*)d_in[12];
  const float* b_hh    = (const float*)d_in[13];
  const float* out_W   = (const float*)d_in[14];
  const float* out_b   = (const float*)d_in[15];

  char* ws = (char*)d_ws;
  u16*   enc_bf = (u16*)(ws + WS_ENC_BF);
  u16*   w2_bf  = (u16*)(ws + WS_W2_BF);
  float* dpw    = (float*)(ws + WS_DPW);
  float* score  = (float*)(ws + WS_SCORE);
  float* gru_in = (float*)(ws + WS_GRUIN);
  float* gi     = (float*)(ws + WS_GI);
  u16*   hA_hi  = (u16*)(ws + WS_HA_HI);
  u16*   hA_lo  = (u16*)(ws + WS_HA_LO);

  float* fc       = (float*)d_out;
  float* h_out    = fc + (long)Bb * Vv;      // 804112
  float* attn_out = h_out + Bb * Hh;         // 820496

  k_cvt2<<<4608, 256, 0, stream>>>(enc_out, enc_bf, w2_W, w2_bf);
  k_prep<<<1024, 256, 0, stream>>>(dec_hs, w1_W, w1_b, w2_b, va_b, x, emb, dpw, score, gru_in);
  k_gemm_score<<<dim3(64, 8), 256, 0, stream>>>(enc_bf, w2_bf, dpw, va_W, score);
  k_softmax<<<16, 256, 0, stream>>>(score, attn_out);
  k_context<<<dim3(16, 32), 256, 0, stream>>>(attn_out, enc_out, gru_in);
  k_gi<<<3072, 256, 0, stream>>>(W_ih, gru_in, b_ih, gi);
  k_gates<<<64, 256, 0, stream>>>(gi, b_hh, h_out, hA_hi, hA_lo);
  k_fc<<<(Vv + 63) / 64, 256, 0, stream>>>(out_W, out_b, hA_hi, hA_lo, fc);
}